// Round 17
// baseline (34967.877 us; speedup 1.0000x reference)
//
#include <hip/hip_runtime.h>

typedef _Float16 f16x8 __attribute__((ext_vector_type(8)));
typedef float f32x4 __attribute__((ext_vector_type(4)));

#define HID   512
#define DXD   256
#define DYD   64
#define NROWS 64
#define NTHR  1024
#define LRC   0.1f
#define TAU1  1e-4f
#define TAU2  1e-4f
#define SC12  2.44140625e-4f   // 2^-12

// ws layout (u16 elements), all fp16 2-plane: h at +0, m(x4096) at +PH
#define OFF_W1YB 0          // [512][64]   W1yB[n][k] = W1[(256+k)*512+n]
#define OFF_W1Y4 32768      // [64][512]   W1y4[d][j] = W1[(256+d)*512+j]
#define OFF_W2B  65536      // [512][512]  W2B[n][k]  = W2[k*512+n]
#define OFF_W2B3 327680     // [512][512]  W2B3[n][k] = W2[n*512+k]
#define PH       589824

// LDS layout (bytes) — STATIC shared so the register allocator sees 1 block/CU
#define L_H0  0             // act plane h [64][512]*2B row stride 1024; x_f32 [64][256]*4B during stage0
#define L_H1  65536         // act plane m
#define HPL   65536
#define L_Y0  131072        // y plane h [64][64]*2B row stride 128
#define L_Y1  139264        // y plane m
#define YPL   8192
#define L_TL  147456        // 64 ints
#define SMEM_BYTES 147712

// fp16 2-plane split: v = h + m*2^-12 (m scaled x4096 to stay normal).
__device__ __forceinline__ void f2h2(float v, unsigned short* ph, unsigned short* pm) {
    unsigned short hb, mb;
    if (fabsf(v) >= 6.103515625e-05f) {
        _Float16 h = (_Float16)v;
        _Float16 m = (_Float16)((v - (float)h) * 4096.0f);
        hb = __builtin_bit_cast(unsigned short, h);
        mb = __builtin_bit_cast(unsigned short, m);
    } else {
        _Float16 m = (_Float16)(v * 4096.0f);
        hb = 0;
        mb = __builtin_bit_cast(unsigned short, m);
    }
    *ph = hb; *pm = mb;
}

// 4mt x 1nq tile GEMM, fp16 2-plane, 3 exact-product terms (low-pressure pass).
// acc += Ah*Bh ; accm += Ah*Bm + Am*Bh  (caller folds accm*2^-12)
template<int KSTEPS, int SROWA, int KDIM, int APL_>
__device__ __forceinline__ void gemmh1(const char* ldsA, const unsigned short* B,
                                       int l4, int l16, int ct,
                                       f32x4 acc[4], f32x4 accm[4])
{
    const int cb0 = l4 * 16;
    #pragma unroll
    for (int kk = 0; kk < KSTEPS; ++kk) {
        const int cb = kk * 64 + cb0;
        f16x8 ah[4], am[4];
        #pragma unroll
        for (int mt = 0; mt < 4; ++mt) {
            const int row = mt * 16 + l16;
            const int off = row * SROWA + (cb ^ ((row & 7) << 4));
            ah[mt] = *(const f16x8*)(ldsA + off);
            am[mt] = *(const f16x8*)(ldsA + APL_ + off);
        }
        const size_t off = (size_t)(ct * 16 + l16) * (KDIM * 2) + cb;
        f16x8 bh = *(const f16x8*)((const char*)B + off);
        f16x8 bm = *(const f16x8*)((const char*)(B + PH) + off);
        #pragma unroll
        for (int mt = 0; mt < 4; ++mt) {
            acc[mt]  = __builtin_amdgcn_mfma_f32_16x16x32_f16(ah[mt], bh, acc[mt],  0, 0, 0);
            accm[mt] = __builtin_amdgcn_mfma_f32_16x16x32_f16(ah[mt], bm, accm[mt], 0, 0, 0);
            accm[mt] = __builtin_amdgcn_mfma_f32_16x16x32_f16(am[mt], bh, accm[mt], 0, 0, 0);
        }
    }
}

// Serial fp32 recompute of a2[row][col] from fp16-2 LDS h1 + fp16-2 W2B row `col`.
// INLINED (r17): noinline ABI boundaries forced caller-saved spill/reload of the
// live set around every potential call -> ~8 GB/dispatch scratch traffic that
// thrashed L2 and evicted the weight tables. Inline bodies sit behind
// s_cbranch_execz and cost nothing when not taken.
__device__ __forceinline__
float rescue_s2(const char* smem, int row, int col, float b2n,
                const unsigned short* __restrict__ wsb) {
    float r = b2n;
    const int xr = (row & 7) << 4;
    const int rb = row * 1024;
    const char* wh = (const char*)(wsb + OFF_W2B) + (size_t)col * 1024;
    const char* wm = (const char*)(wsb + PH + OFF_W2B) + (size_t)col * 1024;
    for (int j0 = 0; j0 < HID; j0 += 8) {
        const int off = rb + ((j0 * 2) ^ xr);
        f16x8 h  = *(const f16x8*)(smem + L_H0 + off);
        f16x8 m_ = *(const f16x8*)(smem + L_H1 + off);
        f16x8 bh = *(const f16x8*)(wh + j0 * 2);
        f16x8 bm = *(const f16x8*)(wm + j0 * 2);
        #pragma unroll
        for (int u = 0; u < 8; ++u) {
            float hv = (float)h[u]  + (float)m_[u] * SC12;
            float wv = (float)bh[u] + (float)bm[u] * SC12;
            r = fmaf(hv, wv, r);
        }
    }
    return r;
}

// Serial fp32 recompute of a1[row][col] from exact c and fp16-2 LDS y + W1YB row `col`.
__device__ __forceinline__
float rescue_s1(const char* smem, int row, int col, float cval,
                const unsigned short* __restrict__ wsb) {
    float r = cval;
    const int xr = (row & 7) << 4;
    const int rb = row * 128;
    const char* wh = (const char*)(wsb + OFF_W1YB) + (size_t)col * 128;
    const char* wm = (const char*)(wsb + PH + OFF_W1YB) + (size_t)col * 128;
    for (int j0 = 0; j0 < DYD; j0 += 8) {
        const int off = rb + ((j0 * 2) ^ xr);
        f16x8 h  = *(const f16x8*)(smem + L_Y0 + off);
        f16x8 m_ = *(const f16x8*)(smem + L_Y1 + off);
        f16x8 bh = *(const f16x8*)(wh + j0 * 2);
        f16x8 bm = *(const f16x8*)(wm + j0 * 2);
        #pragma unroll
        for (int u = 0; u < 8; ++u) {
            float yv = (float)h[u]  + (float)m_[u] * SC12;
            float wv = (float)bh[u] + (float)bm[u] * SC12;
            r = fmaf(yv, wv, r);
        }
    }
    return r;
}

__global__ void wconv(const float* __restrict__ W1, const float* __restrict__ W2,
                      unsigned short* __restrict__ wsb)
{
    int i = blockIdx.x * blockDim.x + threadIdx.x;
    if (i >= PH) return;
    float v;
    if (i < OFF_W1Y4)      { int n = i >> 6, k = i & 63;                    v = W1[(256 + k) * 512 + n]; }
    else if (i < OFF_W2B)  { int j = i - OFF_W1Y4, d = j >> 9, k = j & 511; v = W1[(256 + d) * 512 + k]; }
    else if (i < OFF_W2B3) { int j = i - OFF_W2B,  n = j >> 9, k = j & 511; v = W2[k * 512 + n]; }
    else                   { int j = i - OFF_W2B3, n = j >> 9, k = j & 511; v = W2[n * 512 + k]; }
    f2h2(v, &wsb[i], &wsb[i + PH]);
}

__global__ __attribute__((amdgpu_flat_work_group_size(NTHR, NTHR), amdgpu_waves_per_eu(4, 4)))
void ebm_mfma(const float* __restrict__ x, const int* __restrict__ tt,
              const float* __restrict__ W1, const float* __restrict__ b1,
              const float* __restrict__ W2, const float* __restrict__ b2,
              const float* __restrict__ W3, const int* __restrict__ stepsp,
              const unsigned short* __restrict__ wsb, float* __restrict__ out)
{
    __shared__ __align__(16) char smem[SMEM_BYTES];   // STATIC: allocator sees 1 block/CU

    const int tid  = threadIdx.x;
    const int w    = tid >> 6, lane = tid & 63;   // 16 waves
    const int l4   = lane >> 4, l16 = lane & 15;
    const int r0   = blockIdx.x * NROWS;
    const int nt0  = w * 2;          // wave's 2 16-col tiles (32 cols)
    const int nsteps = *stepsp;

    if (tid < NROWS) {
        int tv = tt[r0 + tid];
        ((int*)(smem + L_TL))[tid] = tv < 0 ? 0 : tv;
    }
    // zero y planes (2 * 8KB)
    for (int i = tid; i < 2 * YPL / 4; i += NTHR) ((unsigned*)(smem + L_Y0))[i] = 0u;

    // stage x -> fp32 [64][256] (row stride 1024B) in L_H0/L_H1 region
    {
        const float4* xg = (const float4*)(x + (size_t)r0 * DXD);
        #pragma unroll
        for (int j = 0; j < 4; ++j) {
            int i4 = j * NTHR + tid;          // 4096 float4 = 64 rows * 64
            ((float4*)(smem + L_H0))[i4] = xg[i4];
        }
    }
    __syncthreads();

    // ---- stage 0: c = x @ W1x + b1, EXACT fp32 VALU (per-element chain identical to r6/r9)
    f32x4 c_reg[4][2];
    {
        float bb[2];
        #pragma unroll
        for (int nq = 0; nq < 2; ++nq) bb[nq] = b1[(nt0 + nq) * 16 + l16];
        #pragma unroll
        for (int mt = 0; mt < 4; ++mt)
            #pragma unroll
            for (int nq = 0; nq < 2; ++nq)
                c_reg[mt][nq] = (f32x4){bb[nq], bb[nq], bb[nq], bb[nq]};
        for (int i = 0; i < DXD; i += 4) {
            float wv[4][2];
            #pragma unroll
            for (int d = 0; d < 4; ++d)
                #pragma unroll
                for (int nq = 0; nq < 2; ++nq)
                    wv[d][nq] = W1[(size_t)(i + d) * HID + (nt0 + nq) * 16 + l16];
            #pragma unroll
            for (int mt = 0; mt < 4; ++mt)
                #pragma unroll
                for (int q = 0; q < 4; ++q) {
                    const int row = mt * 16 + l4 * 4 + q;
                    float4 xv = *(const float4*)(smem + L_H0 + row * 1024 + i * 4);
                    #pragma unroll
                    for (int nq = 0; nq < 2; ++nq) {
                        c_reg[mt][nq][q] = fmaf(xv.x, wv[0][nq], c_reg[mt][nq][q]);
                        c_reg[mt][nq][q] = fmaf(xv.y, wv[1][nq], c_reg[mt][nq][q]);
                        c_reg[mt][nq][q] = fmaf(xv.z, wv[2][nq], c_reg[mt][nq][q]);
                        c_reg[mt][nq][q] = fmaf(xv.w, wv[3][nq], c_reg[mt][nq][q]);
                    }
                }
        }
    }

    float b2v[2];
    #pragma unroll
    for (int nq = 0; nq < 2; ++nq) b2v[nq] = b2[(nt0 + nq) * 16 + l16];

    // S4: one 16x16 tile per wave: rows mt4*16.., cols nt4*16..
    const int mt4 = w >> 2;
    const int nt4 = w & 3;
    f32x4 ym = (f32x4){0.f, 0.f, 0.f, 0.f};

    for (int s = 0; s < nsteps; ++s) {
        __syncthreads();   // prev S4 act reads + y writes done

        // ---- S1: a1 = c + y @ W1y ; rescue ties ; h1 = relu -> fp16-2 planes
        unsigned mk = 0u;
        {   // pass nq=0
            f32x4 acc[4], accm[4];
            #pragma unroll
            for (int mt = 0; mt < 4; ++mt) { acc[mt] = c_reg[mt][0]; accm[mt] = (f32x4){0.f,0.f,0.f,0.f}; }
            gemmh1<2, 128, 64, YPL>(smem + L_Y0, wsb + OFF_W1YB, l4, l16, nt0 + 0, acc, accm);
            const int col = (nt0 + 0) * 16 + l16;
            #pragma unroll
            for (int mt = 0; mt < 4; ++mt) {
                #pragma unroll
                for (int q = 0; q < 4; ++q) {
                    const int row = mt * 16 + l4 * 4 + q;
                    float v = acc[mt][q] + accm[mt][q] * SC12;
                    if (fabsf(v) < TAU1) v = rescue_s1(smem, row, col, c_reg[mt][0][q], wsb);
                    const int off = row * 1024 + ((col * 2) ^ ((row & 7) << 4));
                    if (v > 0.f) {
                        mk |= 1u << ((mt * 2 + 0) * 4 + q);
                        f2h2(v, (unsigned short*)(smem + L_H0 + off), (unsigned short*)(smem + L_H1 + off));
                    } else {
                        *(unsigned short*)(smem + L_H0 + off) = 0;
                        *(unsigned short*)(smem + L_H1 + off) = 0;
                    }
                }
            }
        }
        __builtin_amdgcn_sched_barrier(0);
        {   // pass nq=1
            f32x4 acc[4], accm[4];
            #pragma unroll
            for (int mt = 0; mt < 4; ++mt) { acc[mt] = c_reg[mt][1]; accm[mt] = (f32x4){0.f,0.f,0.f,0.f}; }
            gemmh1<2, 128, 64, YPL>(smem + L_Y0, wsb + OFF_W1YB, l4, l16, nt0 + 1, acc, accm);
            const int col = (nt0 + 1) * 16 + l16;
            #pragma unroll
            for (int mt = 0; mt < 4; ++mt) {
                #pragma unroll
                for (int q = 0; q < 4; ++q) {
                    const int row = mt * 16 + l4 * 4 + q;
                    float v = acc[mt][q] + accm[mt][q] * SC12;
                    if (fabsf(v) < TAU1) v = rescue_s1(smem, row, col, c_reg[mt][1][q], wsb);
                    const int off = row * 1024 + ((col * 2) ^ ((row & 7) << 4));
                    if (v > 0.f) {
                        mk |= 1u << ((mt * 2 + 1) * 4 + q);
                        f2h2(v, (unsigned short*)(smem + L_H0 + off), (unsigned short*)(smem + L_H1 + off));
                    } else {
                        *(unsigned short*)(smem + L_H0 + off) = 0;
                        *(unsigned short*)(smem + L_H1 + off) = 0;
                    }
                }
            }
        }
        __syncthreads();

        // ---- S2: a2 = h1 @ W2 + b2 ; rescue ties -> pos2 bits (two passes)
        unsigned pos2 = 0u;
        {   // pass nq=0
            f32x4 acc[4], accm[4];
            #pragma unroll
            for (int mt = 0; mt < 4; ++mt) { acc[mt] = (f32x4){b2v[0],b2v[0],b2v[0],b2v[0]}; accm[mt] = (f32x4){0.f,0.f,0.f,0.f}; }
            gemmh1<16, 1024, 512, HPL>(smem + L_H0, wsb + OFF_W2B, l4, l16, nt0 + 0, acc, accm);
            const int col = (nt0 + 0) * 16 + l16;
            #pragma unroll
            for (int mt = 0; mt < 4; ++mt) {
                #pragma unroll
                for (int q = 0; q < 4; ++q) {
                    const int row = mt * 16 + l4 * 4 + q;
                    float v = acc[mt][q] + accm[mt][q] * SC12;
                    if (fabsf(v) < TAU2) v = rescue_s2(smem, row, col, b2v[0], wsb);
                    if (v > 0.f) pos2 |= 1u << ((mt * 2 + 0) * 4 + q);
                }
            }
        }
        __builtin_amdgcn_sched_barrier(0);
        {   // pass nq=1
            f32x4 acc[4], accm[4];
            #pragma unroll
            for (int mt = 0; mt < 4; ++mt) { acc[mt] = (f32x4){b2v[1],b2v[1],b2v[1],b2v[1]}; accm[mt] = (f32x4){0.f,0.f,0.f,0.f}; }
            gemmh1<16, 1024, 512, HPL>(smem + L_H0, wsb + OFF_W2B, l4, l16, nt0 + 1, acc, accm);
            const int col = (nt0 + 1) * 16 + l16;
            #pragma unroll
            for (int mt = 0; mt < 4; ++mt) {
                #pragma unroll
                for (int q = 0; q < 4; ++q) {
                    const int row = mt * 16 + l4 * 4 + q;
                    float v = acc[mt][q] + accm[mt][q] * SC12;
                    if (fabsf(v) < TAU2) v = rescue_s2(smem, row, col, b2v[1], wsb);
                    if (v > 0.f) pos2 |= 1u << ((mt * 2 + 1) * 4 + q);
                }
            }
        }
        __syncthreads();   // all h1 reads (gemm + rescue) done

        // S2 epi: m2 = pos ? W3[col][t_row] : 0 -> fp16-2 planes (exact gather)
        #pragma unroll
        for (int mt = 0; mt < 4; ++mt) {
            #pragma unroll
            for (int nq = 0; nq < 2; ++nq) {
                const int col = (nt0 + nq) * 16 + l16;
                #pragma unroll
                for (int q = 0; q < 4; ++q) {
                    const int row = mt * 16 + l4 * 4 + q;
                    const int tv = ((const int*)(smem + L_TL))[row];
                    const int off = row * 1024 + ((col * 2) ^ ((row & 7) << 4));
                    if ((pos2 >> ((mt * 2 + nq) * 4 + q)) & 1u) {
                        f2h2(W3[col * 4 + tv],
                             (unsigned short*)(smem + L_H0 + off),
                             (unsigned short*)(smem + L_H1 + off));
                    } else {
                        *(unsigned short*)(smem + L_H0 + off) = 0;
                        *(unsigned short*)(smem + L_H1 + off) = 0;
                    }
                }
            }
        }
        __syncthreads();

        // ---- S3: g2 = m2 @ W2^T (two passes; g2 held in 2x16 regs) ; m1 -> planes
        f32x4 g2vA[4], g2vB[4];
        {   // pass nq=0
            f32x4 acc[4], accm[4];
            #pragma unroll
            for (int mt = 0; mt < 4; ++mt) { acc[mt] = (f32x4){0.f,0.f,0.f,0.f}; accm[mt] = (f32x4){0.f,0.f,0.f,0.f}; }
            gemmh1<16, 1024, 512, HPL>(smem + L_H0, wsb + OFF_W2B3, l4, l16, nt0 + 0, acc, accm);
            #pragma unroll
            for (int mt = 0; mt < 4; ++mt)
                #pragma unroll
                for (int q = 0; q < 4; ++q)
                    g2vA[mt][q] = acc[mt][q] + accm[mt][q] * SC12;
        }
        __builtin_amdgcn_sched_barrier(0);
        {   // pass nq=1
            f32x4 acc[4], accm[4];
            #pragma unroll
            for (int mt = 0; mt < 4; ++mt) { acc[mt] = (f32x4){0.f,0.f,0.f,0.f}; accm[mt] = (f32x4){0.f,0.f,0.f,0.f}; }
            gemmh1<16, 1024, 512, HPL>(smem + L_H0, wsb + OFF_W2B3, l4, l16, nt0 + 1, acc, accm);
            #pragma unroll
            for (int mt = 0; mt < 4; ++mt)
                #pragma unroll
                for (int q = 0; q < 4; ++q)
                    g2vB[mt][q] = acc[mt][q] + accm[mt][q] * SC12;
        }
        __syncthreads();   // all m2 reads done

        #pragma unroll
        for (int mt = 0; mt < 4; ++mt) {
            {   // nq=0 from g2vA
                const int col2 = ((nt0 + 0) * 16 + l16) * 2;
                #pragma unroll
                for (int q = 0; q < 4; ++q) {
                    const int row = mt * 16 + l4 * 4 + q;
                    const int off = row * 1024 + (col2 ^ ((row & 7) << 4));
                    if ((mk >> ((mt * 2 + 0) * 4 + q)) & 1u) {
                        f2h2(g2vA[mt][q],
                             (unsigned short*)(smem + L_H0 + off),
                             (unsigned short*)(smem + L_H1 + off));
                    } else {
                        *(unsigned short*)(smem + L_H0 + off) = 0;
                        *(unsigned short*)(smem + L_H1 + off) = 0;
                    }
                }
            }
            {   // nq=1 from g2vB
                const int col2 = ((nt0 + 1) * 16 + l16) * 2;
                #pragma unroll
                for (int q = 0; q < 4; ++q) {
                    const int row = mt * 16 + l4 * 4 + q;
                    const int off = row * 1024 + (col2 ^ ((row & 7) << 4));
                    if ((mk >> ((mt * 2 + 1) * 4 + q)) & 1u) {
                        f2h2(g2vB[mt][q],
                             (unsigned short*)(smem + L_H0 + off),
                             (unsigned short*)(smem + L_H1 + off));
                    } else {
                        *(unsigned short*)(smem + L_H0 + off) = 0;
                        *(unsigned short*)(smem + L_H1 + off) = 0;
                    }
                }
            }
        }
        __syncthreads();

        // ---- S4: grad = m1 @ W1y^T (1 tile/wave) ; y -= LR*grad ; refresh y planes
        f32x4 gA = (f32x4){0.f, 0.f, 0.f, 0.f}, gAm = gA;
        {
            const char* bh = (const char*)(wsb + OFF_W1Y4);
            const char* bm = (const char*)(wsb + PH + OFF_W1Y4);
            #pragma unroll
            for (int kk = 0; kk < 16; ++kk) {
                const int cb = kk * 64 + l4 * 16;
                const int row = mt4 * 16 + l16;
                const int offA = row * 1024 + (cb ^ ((row & 7) << 4));
                f16x8 ah = *(const f16x8*)(smem + L_H0 + offA);
                f16x8 am = *(const f16x8*)(smem + L_H1 + offA);
                const size_t obA = (size_t)(nt4 * 16 + l16) * 1024 + cb;
                f16x8 bAh = *(const f16x8*)(bh + obA);
                f16x8 bAm = *(const f16x8*)(bm + obA);
                gA  = __builtin_amdgcn_mfma_f32_16x16x32_f16(ah, bAh, gA,  0, 0, 0);
                gAm = __builtin_amdgcn_mfma_f32_16x16x32_f16(ah, bAm, gAm, 0, 0, 0);
                gAm = __builtin_amdgcn_mfma_f32_16x16x32_f16(am, bAh, gAm, 0, 0, 0);
            }
        }
        #pragma unroll
        for (int q = 0; q < 4; ++q)
            ym[q] = ym[q] - LRC * (gA[q] + gAm[q] * SC12);
        #pragma unroll
        for (int q = 0; q < 4; ++q) {
            const int row = mt4 * 16 + l4 * 4 + q;
            const int col = nt4 * 16 + l16;
            const int off = row * 128 + ((col * 2) ^ ((row & 7) << 4));
            f2h2(ym[q], (unsigned short*)(smem + L_Y0 + off),
                        (unsigned short*)(smem + L_Y1 + off));
        }
    }

    // write out from fp32 register master
    #pragma unroll
    for (int q = 0; q < 4; ++q) {
        const int row = mt4 * 16 + l4 * 4 + q;
        const int col = nt4 * 16 + l16;
        out[(size_t)(r0 + row) * DYD + col] = ym[q];
    }
}

extern "C" void kernel_launch(void* const* d_in, const int* in_sizes, int n_in,
                              void* d_out, int out_size, void* d_ws, size_t ws_size,
                              hipStream_t stream) {
    const float* x  = (const float*)d_in[0];
    const int*   t  = (const int*)d_in[1];
    const float* W1 = (const float*)d_in[2];
    const float* b1 = (const float*)d_in[3];
    const float* W2 = (const float*)d_in[4];
    const float* b2 = (const float*)d_in[5];
    const float* W3 = (const float*)d_in[6];
    // d_in[7] = b3: constant offset, no effect on grad_y
    const int* steps = (const int*)d_in[8];
    float* out = (float*)d_out;
    unsigned short* wsb = (unsigned short*)d_ws;

    const int B = in_sizes[0] / DXD;
    const int nblocks = B / NROWS;

    wconv<<<(PH + 255) / 256, 256, 0, stream>>>(W1, W2, wsb);

    ebm_mfma<<<nblocks, NTHR, 0, stream>>>(x, t, W1, b1, W2, b2, W3, steps, wsb, out);
}

// Round 18
// 26522.647 us; speedup vs baseline: 1.3184x; 1.3184x over previous
//
#include <hip/hip_runtime.h>

typedef _Float16 f16x8 __attribute__((ext_vector_type(8)));
typedef float f32x4 __attribute__((ext_vector_type(4)));

#define HID   512
#define DXD   256
#define DYD   64
#define NROWS 64
#define NTHR  1024
#define LRC   0.1f
#define TAU1  1e-4f
#define TAU2  1e-4f
#define SC12  2.44140625e-4f   // 2^-12

// ws layout (u16 elements), all fp16 2-plane: h at +0, m(x4096) at +PH
#define OFF_W1YB 0          // [512][64]   W1yB[n][k] = W1[(256+k)*512+n]
#define OFF_W1Y4 32768      // [64][512]   W1y4[d][j] = W1[(256+d)*512+j]
#define OFF_W2B  65536      // [512][512]  W2B[n][k]  = W2[k*512+n]
#define OFF_W2B3 327680     // [512][512]  W2B3[n][k] = W2[n*512+k]
#define PH       589824

// LDS layout (bytes) — STATIC shared so the register allocator sees 1 block/CU
#define L_H0  0             // act plane h [64][512]*2B row stride 1024; x_f32 [64][256]*4B during stage0
#define L_H1  65536         // act plane m
#define HPL   65536
#define L_Y0  131072        // y plane h [64][64]*2B row stride 128
#define L_Y1  139264        // y plane m
#define YPL   8192
#define L_TL  147456        // 64 ints
#define SMEM_BYTES 147712

// fp16 2-plane split: v = h + m*2^-12 (m scaled x4096 to stay normal).
__device__ __forceinline__ void f2h2(float v, unsigned short* ph, unsigned short* pm) {
    unsigned short hb, mb;
    if (fabsf(v) >= 6.103515625e-05f) {
        _Float16 h = (_Float16)v;
        _Float16 m = (_Float16)((v - (float)h) * 4096.0f);
        hb = __builtin_bit_cast(unsigned short, h);
        mb = __builtin_bit_cast(unsigned short, m);
    } else {
        _Float16 m = (_Float16)(v * 4096.0f);
        hb = 0;
        mb = __builtin_bit_cast(unsigned short, m);
    }
    *ph = hb; *pm = mb;
}

// 4mt x 1nq tile GEMM, fp16 2-plane, 3 exact-product terms (low-pressure pass).
template<int KSTEPS, int SROWA, int KDIM, int APL_>
__device__ __forceinline__ void gemmh1(const char* ldsA, const unsigned short* B,
                                       int l4, int l16, int ct,
                                       f32x4 acc[4], f32x4 accm[4])
{
    const int cb0 = l4 * 16;
    #pragma unroll
    for (int kk = 0; kk < KSTEPS; ++kk) {
        const int cb = kk * 64 + cb0;
        f16x8 ah[4], am[4];
        #pragma unroll
        for (int mt = 0; mt < 4; ++mt) {
            const int row = mt * 16 + l16;
            const int off = row * SROWA + (cb ^ ((row & 7) << 4));
            ah[mt] = *(const f16x8*)(ldsA + off);
            am[mt] = *(const f16x8*)(ldsA + APL_ + off);
        }
        const size_t off = (size_t)(ct * 16 + l16) * (KDIM * 2) + cb;
        f16x8 bh = *(const f16x8*)((const char*)B + off);
        f16x8 bm = *(const f16x8*)((const char*)(B + PH) + off);
        #pragma unroll
        for (int mt = 0; mt < 4; ++mt) {
            acc[mt]  = __builtin_amdgcn_mfma_f32_16x16x32_f16(ah[mt], bh, acc[mt],  0, 0, 0);
            accm[mt] = __builtin_amdgcn_mfma_f32_16x16x32_f16(ah[mt], bm, accm[mt], 0, 0, 0);
            accm[mt] = __builtin_amdgcn_mfma_f32_16x16x32_f16(am[mt], bh, accm[mt], 0, 0, 0);
        }
    }
}

// Serial fp32 recompute of a2[row][col]. noinline: the call sits inside a
// rarely-taken tie branch, so ABI saves execute ~never (r18 deferred-rescue).
__device__ __attribute__((noinline))
float rescue_s2(const char* smem, int row, int col, float b2n,
                const unsigned short* __restrict__ wsb) {
    float r = b2n;
    const int xr = (row & 7) << 4;
    const int rb = row * 1024;
    const char* wh = (const char*)(wsb + OFF_W2B) + (size_t)col * 1024;
    const char* wm = (const char*)(wsb + PH + OFF_W2B) + (size_t)col * 1024;
    for (int j0 = 0; j0 < HID; j0 += 8) {
        const int off = rb + ((j0 * 2) ^ xr);
        f16x8 h  = *(const f16x8*)(smem + L_H0 + off);
        f16x8 m_ = *(const f16x8*)(smem + L_H1 + off);
        f16x8 bh = *(const f16x8*)(wh + j0 * 2);
        f16x8 bm = *(const f16x8*)(wm + j0 * 2);
        #pragma unroll
        for (int u = 0; u < 8; ++u) {
            float hv = (float)h[u]  + (float)m_[u] * SC12;
            float wv = (float)bh[u] + (float)bm[u] * SC12;
            r = fmaf(hv, wv, r);
        }
    }
    return r;
}

__device__ __attribute__((noinline))
float rescue_s1(const char* smem, int row, int col, float cval,
                const unsigned short* __restrict__ wsb) {
    float r = cval;
    const int xr = (row & 7) << 4;
    const int rb = row * 128;
    const char* wh = (const char*)(wsb + OFF_W1YB) + (size_t)col * 128;
    const char* wm = (const char*)(wsb + PH + OFF_W1YB) + (size_t)col * 128;
    for (int j0 = 0; j0 < DYD; j0 += 8) {
        const int off = rb + ((j0 * 2) ^ xr);
        f16x8 h  = *(const f16x8*)(smem + L_Y0 + off);
        f16x8 m_ = *(const f16x8*)(smem + L_Y1 + off);
        f16x8 bh = *(const f16x8*)(wh + j0 * 2);
        f16x8 bm = *(const f16x8*)(wm + j0 * 2);
        #pragma unroll
        for (int u = 0; u < 8; ++u) {
            float yv = (float)h[u]  + (float)m_[u] * SC12;
            float wv = (float)bh[u] + (float)bm[u] * SC12;
            r = fmaf(yv, wv, r);
        }
    }
    return r;
}

__global__ void wconv(const float* __restrict__ W1, const float* __restrict__ W2,
                      unsigned short* __restrict__ wsb)
{
    int i = blockIdx.x * blockDim.x + threadIdx.x;
    if (i >= PH) return;
    float v;
    if (i < OFF_W1Y4)      { int n = i >> 6, k = i & 63;                    v = W1[(256 + k) * 512 + n]; }
    else if (i < OFF_W2B)  { int j = i - OFF_W1Y4, d = j >> 9, k = j & 511; v = W1[(256 + d) * 512 + k]; }
    else if (i < OFF_W2B3) { int j = i - OFF_W2B,  n = j >> 9, k = j & 511; v = W2[k * 512 + n]; }
    else                   { int j = i - OFF_W2B3, n = j >> 9, k = j & 511; v = W2[n * 512 + k]; }
    f2h2(v, &wsb[i], &wsb[i + PH]);
}

__global__ __attribute__((amdgpu_flat_work_group_size(NTHR, NTHR), amdgpu_waves_per_eu(4, 4)))
void ebm_mfma(const float* __restrict__ x, const int* __restrict__ tt,
              const float* __restrict__ W1, const float* __restrict__ b1,
              const float* __restrict__ W2, const float* __restrict__ b2,
              const float* __restrict__ W3, const int* __restrict__ stepsp,
              const unsigned short* __restrict__ wsb, float* __restrict__ out)
{
    __shared__ __align__(16) char smem[SMEM_BYTES];

    const int tid  = threadIdx.x;
    const int w    = tid >> 6, lane = tid & 63;   // 16 waves
    const int l4   = lane >> 4, l16 = lane & 15;
    const int r0   = blockIdx.x * NROWS;
    const int nt0  = w * 2;          // wave's 2 16-col tiles (32 cols)
    const int nsteps = *stepsp;

    if (tid < NROWS) {
        int tv = tt[r0 + tid];
        ((int*)(smem + L_TL))[tid] = tv < 0 ? 0 : tv;
    }
    for (int i = tid; i < 2 * YPL / 4; i += NTHR) ((unsigned*)(smem + L_Y0))[i] = 0u;

    // stage x -> fp32 [64][256] (row stride 1024B) in L_H0/L_H1 region
    {
        const float4* xg = (const float4*)(x + (size_t)r0 * DXD);
        #pragma unroll
        for (int j = 0; j < 4; ++j) {
            int i4 = j * NTHR + tid;
            ((float4*)(smem + L_H0))[i4] = xg[i4];
        }
    }
    __syncthreads();

    // ---- stage 0: c = x @ W1x + b1, EXACT fp32 VALU (per-element chain identical to r6/r9)
    f32x4 c_reg[4][2];
    {
        float bb[2];
        #pragma unroll
        for (int nq = 0; nq < 2; ++nq) bb[nq] = b1[(nt0 + nq) * 16 + l16];
        #pragma unroll
        for (int mt = 0; mt < 4; ++mt)
            #pragma unroll
            for (int nq = 0; nq < 2; ++nq)
                c_reg[mt][nq] = (f32x4){bb[nq], bb[nq], bb[nq], bb[nq]};
        for (int i = 0; i < DXD; i += 4) {
            float wv[4][2];
            #pragma unroll
            for (int d = 0; d < 4; ++d)
                #pragma unroll
                for (int nq = 0; nq < 2; ++nq)
                    wv[d][nq] = W1[(size_t)(i + d) * HID + (nt0 + nq) * 16 + l16];
            #pragma unroll
            for (int mt = 0; mt < 4; ++mt)
                #pragma unroll
                for (int q = 0; q < 4; ++q) {
                    const int row = mt * 16 + l4 * 4 + q;
                    float4 xv = *(const float4*)(smem + L_H0 + row * 1024 + i * 4);
                    #pragma unroll
                    for (int nq = 0; nq < 2; ++nq) {
                        c_reg[mt][nq][q] = fmaf(xv.x, wv[0][nq], c_reg[mt][nq][q]);
                        c_reg[mt][nq][q] = fmaf(xv.y, wv[1][nq], c_reg[mt][nq][q]);
                        c_reg[mt][nq][q] = fmaf(xv.z, wv[2][nq], c_reg[mt][nq][q]);
                        c_reg[mt][nq][q] = fmaf(xv.w, wv[3][nq], c_reg[mt][nq][q]);
                    }
                }
        }
    }

    float b2v[2];
    #pragma unroll
    for (int nq = 0; nq < 2; ++nq) b2v[nq] = b2[(nt0 + nq) * 16 + l16];

    const int mt4 = w >> 2;
    const int nt4 = w & 3;
    f32x4 ym = (f32x4){0.f, 0.f, 0.f, 0.f};

    for (int s = 0; s < nsteps; ++s) {
        __syncthreads();   // prev S4 act reads + y writes done

        // ---- S1: a1 = c + y @ W1y ; deferred tie-rescue ; h1 = relu -> fp16-2 planes
        unsigned mk = 0u;
        #pragma unroll
        for (int nq = 0; nq < 2; ++nq) {
            f32x4 acc[4], accm[4];
            #pragma unroll
            for (int mt = 0; mt < 4; ++mt) { acc[mt] = c_reg[mt][nq]; accm[mt] = (f32x4){0.f,0.f,0.f,0.f}; }
            gemmh1<2, 128, 64, YPL>(smem + L_Y0, wsb + OFF_W1YB, l4, l16, nt0 + nq, acc, accm);
            const int col = (nt0 + nq) * 16 + l16;
            // phase 1: fold, preliminary write, record ties (no rescue in hot path)
            f32x4 v4[4];
            unsigned tie = 0u;
            #pragma unroll
            for (int mt = 0; mt < 4; ++mt) {
                #pragma unroll
                for (int q = 0; q < 4; ++q) {
                    const int row = mt * 16 + l4 * 4 + q;
                    float v = acc[mt][q] + accm[mt][q] * SC12;
                    v4[mt][q] = v;
                    if (fabsf(v) < TAU1) tie |= 1u << (mt * 4 + q);
                    const int off = row * 1024 + ((col * 2) ^ ((row & 7) << 4));
                    if (v > 0.f) {
                        mk |= 1u << ((mt * 2 + nq) * 4 + q);
                        f2h2(v, (unsigned short*)(smem + L_H0 + off), (unsigned short*)(smem + L_H1 + off));
                    } else {
                        *(unsigned short*)(smem + L_H0 + off) = 0;
                        *(unsigned short*)(smem + L_H1 + off) = 0;
                    }
                }
            }
            // phase 2: rare fix-up (acc/accm dead; rescue call inside branch)
            if (__builtin_expect(tie != 0u, 0)) {
                #pragma unroll
                for (int mt = 0; mt < 4; ++mt) {
                    #pragma unroll
                    for (int q = 0; q < 4; ++q) {
                        if ((tie >> (mt * 4 + q)) & 1u) {
                            const int row = mt * 16 + l4 * 4 + q;
                            const float vr = rescue_s1(smem, row, col, c_reg[mt][nq][q], wsb);
                            const int off = row * 1024 + ((col * 2) ^ ((row & 7) << 4));
                            const unsigned bit = 1u << ((mt * 2 + nq) * 4 + q);
                            if (vr > 0.f) {
                                mk |= bit;
                                f2h2(vr, (unsigned short*)(smem + L_H0 + off), (unsigned short*)(smem + L_H1 + off));
                            } else {
                                mk &= ~bit;
                                *(unsigned short*)(smem + L_H0 + off) = 0;
                                *(unsigned short*)(smem + L_H1 + off) = 0;
                            }
                        }
                    }
                }
            }
            __builtin_amdgcn_sched_barrier(0);
        }
        __syncthreads();

        // ---- S2: a2 = h1 @ W2 + b2 ; deferred tie-rescue -> pos2 bits
        unsigned pos2 = 0u;
        #pragma unroll
        for (int nq = 0; nq < 2; ++nq) {
            f32x4 acc[4], accm[4];
            #pragma unroll
            for (int mt = 0; mt < 4; ++mt) { acc[mt] = (f32x4){b2v[nq],b2v[nq],b2v[nq],b2v[nq]}; accm[mt] = (f32x4){0.f,0.f,0.f,0.f}; }
            gemmh1<16, 1024, 512, HPL>(smem + L_H0, wsb + OFF_W2B, l4, l16, nt0 + nq, acc, accm);
            const int col = (nt0 + nq) * 16 + l16;
            unsigned tie = 0u;
            #pragma unroll
            for (int mt = 0; mt < 4; ++mt) {
                #pragma unroll
                for (int q = 0; q < 4; ++q) {
                    float v = acc[mt][q] + accm[mt][q] * SC12;
                    if (fabsf(v) < TAU2) tie |= 1u << (mt * 4 + q);
                    if (v > 0.f) pos2 |= 1u << ((mt * 2 + nq) * 4 + q);
                }
            }
            if (__builtin_expect(tie != 0u, 0)) {
                #pragma unroll
                for (int mt = 0; mt < 4; ++mt) {
                    #pragma unroll
                    for (int q = 0; q < 4; ++q) {
                        if ((tie >> (mt * 4 + q)) & 1u) {
                            const int row = mt * 16 + l4 * 4 + q;
                            const float vr = rescue_s2(smem, row, col, b2v[nq], wsb);
                            const unsigned bit = 1u << ((mt * 2 + nq) * 4 + q);
                            if (vr > 0.f) pos2 |= bit; else pos2 &= ~bit;
                        }
                    }
                }
            }
            __builtin_amdgcn_sched_barrier(0);
        }
        __syncthreads();   // all h1 reads (gemm + rescue) done

        // S2 epi: m2 = pos ? W3[col][t_row] : 0 -> fp16-2 planes (exact gather)
        #pragma unroll
        for (int mt = 0; mt < 4; ++mt) {
            #pragma unroll
            for (int nq = 0; nq < 2; ++nq) {
                const int col = (nt0 + nq) * 16 + l16;
                #pragma unroll
                for (int q = 0; q < 4; ++q) {
                    const int row = mt * 16 + l4 * 4 + q;
                    const int tv = ((const int*)(smem + L_TL))[row];
                    const int off = row * 1024 + ((col * 2) ^ ((row & 7) << 4));
                    if ((pos2 >> ((mt * 2 + nq) * 4 + q)) & 1u) {
                        f2h2(W3[col * 4 + tv],
                             (unsigned short*)(smem + L_H0 + off),
                             (unsigned short*)(smem + L_H1 + off));
                    } else {
                        *(unsigned short*)(smem + L_H0 + off) = 0;
                        *(unsigned short*)(smem + L_H1 + off) = 0;
                    }
                }
            }
        }
        __syncthreads();

        // ---- S3: g2 = m2 @ W2^T (two passes; g2 held in 2x16 regs) ; m1 -> planes
        f32x4 g2vA[4], g2vB[4];
        {   // pass nq=0
            f32x4 acc[4], accm[4];
            #pragma unroll
            for (int mt = 0; mt < 4; ++mt) { acc[mt] = (f32x4){0.f,0.f,0.f,0.f}; accm[mt] = (f32x4){0.f,0.f,0.f,0.f}; }
            gemmh1<16, 1024, 512, HPL>(smem + L_H0, wsb + OFF_W2B3, l4, l16, nt0 + 0, acc, accm);
            #pragma unroll
            for (int mt = 0; mt < 4; ++mt)
                #pragma unroll
                for (int q = 0; q < 4; ++q)
                    g2vA[mt][q] = acc[mt][q] + accm[mt][q] * SC12;
        }
        __builtin_amdgcn_sched_barrier(0);
        {   // pass nq=1
            f32x4 acc[4], accm[4];
            #pragma unroll
            for (int mt = 0; mt < 4; ++mt) { acc[mt] = (f32x4){0.f,0.f,0.f,0.f}; accm[mt] = (f32x4){0.f,0.f,0.f,0.f}; }
            gemmh1<16, 1024, 512, HPL>(smem + L_H0, wsb + OFF_W2B3, l4, l16, nt0 + 1, acc, accm);
            #pragma unroll
            for (int mt = 0; mt < 4; ++mt)
                #pragma unroll
                for (int q = 0; q < 4; ++q)
                    g2vB[mt][q] = acc[mt][q] + accm[mt][q] * SC12;
        }
        __syncthreads();   // all m2 reads done

        #pragma unroll
        for (int mt = 0; mt < 4; ++mt) {
            {   // nq=0 from g2vA
                const int col2 = ((nt0 + 0) * 16 + l16) * 2;
                #pragma unroll
                for (int q = 0; q < 4; ++q) {
                    const int row = mt * 16 + l4 * 4 + q;
                    const int off = row * 1024 + (col2 ^ ((row & 7) << 4));
                    if ((mk >> ((mt * 2 + 0) * 4 + q)) & 1u) {
                        f2h2(g2vA[mt][q],
                             (unsigned short*)(smem + L_H0 + off),
                             (unsigned short*)(smem + L_H1 + off));
                    } else {
                        *(unsigned short*)(smem + L_H0 + off) = 0;
                        *(unsigned short*)(smem + L_H1 + off) = 0;
                    }
                }
            }
            {   // nq=1 from g2vB
                const int col2 = ((nt0 + 1) * 16 + l16) * 2;
                #pragma unroll
                for (int q = 0; q < 4; ++q) {
                    const int row = mt * 16 + l4 * 4 + q;
                    const int off = row * 1024 + (col2 ^ ((row & 7) << 4));
                    if ((mk >> ((mt * 2 + 1) * 4 + q)) & 1u) {
                        f2h2(g2vB[mt][q],
                             (unsigned short*)(smem + L_H0 + off),
                             (unsigned short*)(smem + L_H1 + off));
                    } else {
                        *(unsigned short*)(smem + L_H0 + off) = 0;
                        *(unsigned short*)(smem + L_H1 + off) = 0;
                    }
                }
            }
        }
        __syncthreads();

        // ---- S4: grad = m1 @ W1y^T (1 tile/wave) ; y -= LR*grad ; refresh y planes
        f32x4 gA = (f32x4){0.f, 0.f, 0.f, 0.f}, gAm = gA;
        {
            const char* bh = (const char*)(wsb + OFF_W1Y4);
            const char* bm = (const char*)(wsb + PH + OFF_W1Y4);
            #pragma unroll
            for (int kk = 0; kk < 16; ++kk) {
                const int cb = kk * 64 + l4 * 16;
                const int row = mt4 * 16 + l16;
                const int offA = row * 1024 + (cb ^ ((row & 7) << 4));
                f16x8 ah = *(const f16x8*)(smem + L_H0 + offA);
                f16x8 am = *(const f16x8*)(smem + L_H1 + offA);
                const size_t obA = (size_t)(nt4 * 16 + l16) * 1024 + cb;
                f16x8 bAh = *(const f16x8*)(bh + obA);
                f16x8 bAm = *(const f16x8*)(bm + obA);
                gA  = __builtin_amdgcn_mfma_f32_16x16x32_f16(ah, bAh, gA,  0, 0, 0);
                gAm = __builtin_amdgcn_mfma_f32_16x16x32_f16(ah, bAm, gAm, 0, 0, 0);
                gAm = __builtin_amdgcn_mfma_f32_16x16x32_f16(am, bAh, gAm, 0, 0, 0);
            }
        }
        #pragma unroll
        for (int q = 0; q < 4; ++q)
            ym[q] = ym[q] - LRC * (gA[q] + gAm[q] * SC12);
        #pragma unroll
        for (int q = 0; q < 4; ++q) {
            const int row = mt4 * 16 + l4 * 4 + q;
            const int col = nt4 * 16 + l16;
            const int off = row * 128 + ((col * 2) ^ ((row & 7) << 4));
            f2h2(ym[q], (unsigned short*)(smem + L_Y0 + off),
                        (unsigned short*)(smem + L_Y1 + off));
        }
    }

    // write out from fp32 register master
    #pragma unroll
    for (int q = 0; q < 4; ++q) {
        const int row = mt4 * 16 + l4 * 4 + q;
        const int col = nt4 * 16 + l16;
        out[(size_t)(r0 + row) * DYD + col] = ym[q];
    }
}

extern "C" void kernel_launch(void* const* d_in, const int* in_sizes, int n_in,
                              void* d_out, int out_size, void* d_ws, size_t ws_size,
                              hipStream_t stream) {
    const float* x  = (const float*)d_in[0];
    const int*   t  = (const int*)d_in[1];
    const float* W1 = (const float*)d_in[2];
    const float* b1 = (const float*)d_in[3];
    const float* W2 = (const float*)d_in[4];
    const float* b2 = (const float*)d_in[5];
    const float* W3 = (const float*)d_in[6];
    // d_in[7] = b3: constant offset, no effect on grad_y
    const int* steps = (const int*)d_in[8];
    float* out = (float*)d_out;
    unsigned short* wsb = (unsigned short*)d_ws;

    const int B = in_sizes[0] / DXD;
    const int nblocks = B / NROWS;

    wconv<<<(PH + 255) / 256, 256, 0, stream>>>(W1, W2, wsb);

    ebm_mfma<<<nblocks, NTHR, 0, stream>>>(x, t, W1, b1, W2, b2, W3, steps, wsb, out);
}